// Round 2
// baseline (627.453 us; speedup 1.0000x reference)
//
#include <hip/hip_runtime.h>
#include <hip/hip_bf16.h>

typedef unsigned short u16;
typedef __bf16 bf16x8 __attribute__((ext_vector_type(8)));
typedef float  f32x4  __attribute__((ext_vector_type(4)));

__device__ __forceinline__ u16 f2b(float f) {
    unsigned u = __float_as_uint(f);
    return (u16)((u + 0x7FFFu + ((u >> 16) & 1u)) >> 16);  // RNE f32->bf16
}
__device__ __forceinline__ float b2f(u16 b) {
    return __uint_as_float(((unsigned)b) << 16);
}
__device__ __forceinline__ unsigned pk2(float a, float b) {
    __hip_bfloat162 h = __float22bfloat162_rn(make_float2(a, b));
    unsigned u;
    __builtin_memcpy(&u, &h, 4);
    return u;   // low 16 = bf16(a), high 16 = bf16(b)
}

// ---------------------------------------------------------------------------
// prep: pp[r][j]  = pos_table[r] . W_pos_w[j,128:256] + W_pos_b[j]   (fp32)
//       wb1[j][k] = bf16(W_pos_w[j][k])  (k<128, GEMM1 B operand, row-major)
//       wb2[j][k] = bf16(W2[j][k])       (GEMM2 B operand, row-major)
// ---------------------------------------------------------------------------
__global__ __launch_bounds__(128) void prep_kernel(
    const float* __restrict__ pos_table, const float* __restrict__ Wpw,
    const float* __restrict__ Wpb, const float* __restrict__ W2,
    float* __restrict__ pp, u16* __restrict__ wb1, u16* __restrict__ wb2)
{
    const int b = blockIdx.x, t = threadIdx.x;
    if (b < 65) {
        const float4* pr = (const float4*)(pos_table + b * 128);
        const float4* wr = (const float4*)(Wpw + t * 256 + 128);
        float acc = Wpb[t];
        #pragma unroll
        for (int k = 0; k < 32; ++k) {
            const float4 p = pr[k], wv = wr[k];
            acc += p.x * wv.x + p.y * wv.y + p.z * wv.z + p.w * wv.w;
        }
        pp[b * 128 + t] = acc;
    } else {
        const int j = b - 65;                      // 0..127
        wb1[j * 128 + t] = f2b(Wpw[j * 256 + t]);
        wb2[j * 128 + t] = f2b(W2[j * 128 + t]);
    }
}

// ---------------------------------------------------------------------------
// fused: one block = one session (64 tokens x 128 hidden)
// LDS ~20.5 KB; __launch_bounds__(256,5) -> 5 blocks/CU (20 waves) target.
// B-fragments for both GEMMs load straight from global (L2-broadcast across
// all 8192 blocks) -- no LDS weight staging.
// ---------------------------------------------------------------------------
__global__ __launch_bounds__(256, 5) void fused_kernel(
    const float* __restrict__ hidden, const int* __restrict__ rpos,
    const float* __restrict__ W1, const float* __restrict__ W1b,
    const float* __restrict__ W2b,
    const float* __restrict__ qw, const float* __restrict__ qb,
    const float* __restrict__ pp, const u16* __restrict__ wb1g,
    const u16* __restrict__ wb2g,
    float* __restrict__ out)
{
    // 64 rows x 136 bf16 (pad +8 breaks 256B bank stride); reused for ph
    __shared__ __align__(16) u16 hbf[64 * 136];     // 17408 B
    __shared__ __align__(16) float meanv[128];
    __shared__ float g1s[128];
    __shared__ float qws[128];
    __shared__ float alphas[64];
    __shared__ int   rps[64];
    __shared__ float partf[256];                    // total ~20.5 KB

    const int tid = threadIdx.x;
    const int s = blockIdx.x;
    const int w = tid >> 6;                 // wave 0..3 (rows 16w..16w+15)
    const int l = tid & 63;
    const int c = l & 15;                   // MFMA A-row / B-row / D-col
    const int g = l >> 4;                   // quad: k-chunk, D-row group
    const float* hsrc = hidden + (size_t)s * (64 * 128);

    // ---- stage hidden (fp32 global -> bf16 LDS), packed cvt, coalesced
    #pragma unroll
    for (int i = 0; i < 8; ++i) {
        const int i4 = tid + i * 256;                 // float4 index 0..2047
        const float4 v = ((const float4*)hsrc)[i4];
        const int e = i4 * 4, row = e >> 7, col = e & 127;
        uint2 st;
        st.x = pk2(v.x, v.y);
        st.y = pk2(v.z, v.w);
        *(uint2*)&hbf[row * 136 + col] = st;
    }
    if (tid < 64)  rps[tid] = rpos[s * 64 + tid];
    if (tid < 128) qws[tid] = qw[tid];
    __syncthreads();

    // ---- per-session mean (bf16 source; error negligible after /64)
    if (tid < 128) {
        float m = 0.f;
        #pragma unroll 8
        for (int t = 0; t < 64; ++t) m += b2f(hbf[t * 136 + tid]);
        meanv[tid] = m * (1.f / 64.f);
    }
    __syncthreads();

    // ---- g1 = mean @ W1^T + W1_b + W2_b (fp32, vectorized row reads of W1;
    //      waves 0-1 do this while waves 2-3 run ahead into GEMM1; the
    //      post-GEMM1 barrier makes g1s visible before its first use)
    if (tid < 128) {
        const float4* wr = (const float4*)(W1 + tid * 128);
        const float4* mv = (const float4*)meanv;
        float acc = W1b[tid] + W2b[tid];
        #pragma unroll 8
        for (int k4 = 0; k4 < 32; ++k4) {
            const float4 wv = wr[k4], m4 = mv[k4];
            acc += m4.x * wv.x + m4.y * wv.y + m4.z * wv.z + m4.w * wv.w;
        }
        g1s[tid] = acc;
    }

    // ---- GEMM1: ph = tanh(hidden @ Wpa^T + pp[rp])   M=16/wave, N=128, K=128
    bf16x8 afr[4];
    #pragma unroll
    for (int kk = 0; kk < 4; ++kk)
        afr[kk] = *(const bf16x8*)&hbf[(16 * w + c) * 136 + kk * 32 + g * 8];
    const u16* b1p = wb1g + c * 128 + g * 8;        // lane's B base
    f32x4 acc1[8] = {};
    #pragma unroll
    for (int n = 0; n < 8; ++n) {
        #pragma unroll
        for (int kk = 0; kk < 4; ++kk) {
            const bf16x8 bfr = *(const bf16x8*)(b1p + n * 2048 + kk * 32);
            acc1[n] = __builtin_amdgcn_mfma_f32_16x16x32_bf16(afr[kk], bfr, acc1[n], 0, 0, 0);
        }
    }
    const float* ppr[4];
    #pragma unroll
    for (int r = 0; r < 4; ++r)
        ppr[r] = pp + rps[16 * w + 4 * g + r] * 128 + c;
    #pragma unroll
    for (int n = 0; n < 8; ++n) {
        const int j = 16 * n + c;
        #pragma unroll
        for (int r = 0; r < 4; ++r) {
            const float v = acc1[n][r] + ppr[r][16 * n];
            const float e2 = exp2f(v * 2.885390081777927f);     // e^(2v)
            const float th = 1.f - 2.f / (e2 + 1.f);            // tanh(v)
            // in-place: rows 16w+4g+r are within this wave's own tile
            hbf[(16 * w + 4 * g + r) * 136 + j] = f2b(th);
        }
    }
    __syncthreads();   // ph committed (cross-lane LDS ordering)

    // ---- GEMM2: gate = sigmoid(g1 + ph @ W2^T); alpha = gate.qw + qb
    bf16x8 af2[4];
    #pragma unroll
    for (int kk = 0; kk < 4; ++kk)
        af2[kk] = *(const bf16x8*)&hbf[(16 * w + c) * 136 + kk * 32 + g * 8];
    const u16* b2p = wb2g + c * 128 + g * 8;
    f32x4 acc2[8] = {};
    #pragma unroll
    for (int n = 0; n < 8; ++n) {
        #pragma unroll
        for (int kk = 0; kk < 4; ++kk) {
            const bf16x8 bfr = *(const bf16x8*)(b2p + n * 2048 + kk * 32);
            acc2[n] = __builtin_amdgcn_mfma_f32_16x16x32_bf16(af2[kk], bfr, acc2[n], 0, 0, 0);
        }
    }
    float prt[4] = {0.f, 0.f, 0.f, 0.f};
    #pragma unroll
    for (int n = 0; n < 8; ++n) {
        const int j = 16 * n + c;
        const float g1j = g1s[j], qwj = qws[j];
        #pragma unroll
        for (int r = 0; r < 4; ++r) {
            const float x = acc2[n][r] + g1j;
            const float gate = 1.f / (1.f + exp2f(-1.4426950408889634f * x));
            prt[r] += gate * qwj;
        }
    }
    // reduce over the 16 D-columns (lanes c=0..15 within each quad-group)
    #pragma unroll
    for (int msk = 1; msk <= 8; msk <<= 1) {
        #pragma unroll
        for (int r = 0; r < 4; ++r) prt[r] += __shfl_xor(prt[r], msk, 64);
    }
    if (c == 0) {
        const float qbv = qb[0];
        #pragma unroll
        for (int r = 0; r < 4; ++r) alphas[16 * w + 4 * g + r] = prt[r] + qbv;
    }
    __syncthreads();

    // ---- out[s] = sum_t alpha_t * hidden[t]  (fp32 from global; L2-hot)
    {
        const int h = tid & 127, p = tid >> 7;
        float accf = 0.f;
        #pragma unroll 8
        for (int t = 32 * p; t < 32 * p + 32; ++t)
            accf += alphas[t] * hsrc[t * 128 + h];
        partf[p * 128 + h] = accf;
    }
    __syncthreads();
    if (tid < 128) out[(size_t)s * 128 + tid] = partf[tid] + partf[128 + tid];
}

// ---------------------------------------------------------------------------
extern "C" void kernel_launch(void* const* d_in, const int* in_sizes, int n_in,
                              void* d_out, int out_size, void* d_ws, size_t ws_size,
                              hipStream_t stream)
{
    const float* hidden    = (const float*)d_in[0];
    const float* pos_table = (const float*)d_in[1];
    const float* Wpw       = (const float*)d_in[2];
    const float* Wpb       = (const float*)d_in[3];
    const float* W1w       = (const float*)d_in[4];
    const float* W1b       = (const float*)d_in[5];
    const float* W2w       = (const float*)d_in[6];
    const float* W2b       = (const float*)d_in[7];
    const float* qw        = (const float*)d_in[8];
    const float* qb        = (const float*)d_in[9];
    const int*   rpos      = (const int*)d_in[11];
    float* out = (float*)d_out;

    const int B = in_sizes[10];              // sessions (8192)

    // workspace layout (98816 B total)
    char* wsb = (char*)d_ws;
    float* pp = (float*)wsb;                         // 65*128*4 = 33280
    u16* wb1  = (u16*)(wsb + 33280);                 // 32768
    u16* wb2  = (u16*)(wsb + 33280 + 32768);         // 32768

    prep_kernel<<<193, 128, 0, stream>>>(pos_table, Wpw, Wpb, W2w,
                                         pp, wb1, wb2);
    fused_kernel<<<B, 256, 0, stream>>>(hidden, rpos, W1w, W1b, W2b, qw, qb,
                                        pp, wb1, wb2, out);
}

// Round 3
// 486.230 us; speedup vs baseline: 1.2904x; 1.2904x over previous
//
#include <hip/hip_runtime.h>
#include <hip/hip_bf16.h>

typedef unsigned short u16;
typedef __bf16 bf16x8 __attribute__((ext_vector_type(8)));
typedef float  f32x4  __attribute__((ext_vector_type(4)));

__device__ __forceinline__ unsigned pk2(float a, float b) {
    __hip_bfloat162 h = __float22bfloat162_rn(make_float2(a, b));
    unsigned u; __builtin_memcpy(&u, &h, 4);
    return u;   // low 16 = bf16(a), high 16 = bf16(b)
}
__device__ __forceinline__ u16 f2b1(float f) { return (u16)(pk2(f, f) & 0xFFFFu); }

#define MFMA __builtin_amdgcn_mfma_f32_16x16x32_bf16

// ---------------------------------------------------------------------------
// prep: ppK[r][j] = (pos_table[r].W_pos_w[j,128:256] + W_pos_b[j]) * 2*log2(e)
//       wb1[j][k] = bf16(W_pos_w[j][k])  (k<128, GEMM1 B operand, row-major)
//       wb2[j][k] = bf16(W2[j][k])       (GEMM2 B operand, row-major)
// ---------------------------------------------------------------------------
__global__ __launch_bounds__(128) void prep_kernel(
    const float* __restrict__ pos_table, const float* __restrict__ Wpw,
    const float* __restrict__ Wpb, const float* __restrict__ W2,
    float* __restrict__ ppK, u16* __restrict__ wb1, u16* __restrict__ wb2)
{
    const int b = blockIdx.x, t = threadIdx.x;
    if (b < 65) {
        const float4* pr = (const float4*)(pos_table + b * 128);
        const float4* wr = (const float4*)(Wpw + t * 256 + 128);
        float acc = Wpb[t];
        #pragma unroll
        for (int k = 0; k < 32; ++k) {
            const float4 p = pr[k], wv = wr[k];
            acc += p.x * wv.x + p.y * wv.y + p.z * wv.z + p.w * wv.w;
        }
        ppK[b * 128 + t] = acc * 2.885390081777927f;   // pre-scaled for exp2
    } else {
        const int j = b - 65;                          // 0..127
        wb1[j * 128 + t] = f2b1(Wpw[j * 256 + t]);
        wb2[j * 128 + t] = f2b1(W2[j * 128 + t]);
    }
}

// ---------------------------------------------------------------------------
// fused: one block = TWO sessions (128 token rows x 128 hidden)
// wave w owns rows 32w..32w+31 (2 m-tiles); session of wave = w>>1.
// Weights LDS-staged (wb1 then wb2); B-frag reused across both m-tiles.
// LDS ~73 KB -> 2 blocks/CU.
// ---------------------------------------------------------------------------
__global__ __launch_bounds__(256, 2) void fused_kernel(
    const float* __restrict__ hidden, const int* __restrict__ rpos,
    const float* __restrict__ W1, const float* __restrict__ W1b,
    const float* __restrict__ W2b, const float* __restrict__ qw,
    const float* __restrict__ qb, const float* __restrict__ ppK,
    const u16* __restrict__ wb1g, const u16* __restrict__ wb2g,
    float* __restrict__ out)
{
    // 128 rows x 136 bf16 (pad +8: 272B row stride, 16B-aligned, 2-way-free)
    __shared__ __align__(16) u16 hbf[128 * 136];    // 34816 B (hidden -> ph)
    __shared__ __align__(16) u16 wb[128 * 136];     // 34816 B (wb1 -> wb2)
    __shared__ float meanv[256];                    // [2][128] fp32 sums
    __shared__ float g1s[256];                      // [2][128]
    __shared__ float qws[128];
    __shared__ float alphas[128];
    __shared__ int   rps[128];                      // total 73216 B

    const int tid = threadIdx.x;
    const int blk = blockIdx.x;
    const int w = tid >> 6;                 // wave 0..3, rows 32w..32w+31
    const int l = tid & 63;
    const int c = l & 15;                   // MFMA A-row / B-row / D-col
    const int g = l >> 4;                   // quad
    const int R = 32 * w;
    const float* hsrc = hidden + (size_t)blk * (128 * 128);

    // ---- phase 0: zero mean accumulators, stage small vectors
    meanv[tid] = 0.f;
    if (tid < 128) { rps[tid] = rpos[blk * 128 + tid]; qws[tid] = qw[tid]; }
    __syncthreads();

    // ---- phase 1: hidden -> bf16 LDS; fp32 column sums via ds_add_f32.
    // Thread's 16 chunks all hit column group (4*tid)&127: rows (tid>>5)+8i,
    // i<8 -> session 0, i>=8 -> session 1. Register-accumulate, 8 atomics.
    {
        float4 ms0 = {0.f, 0.f, 0.f, 0.f}, ms1 = {0.f, 0.f, 0.f, 0.f};
        #pragma unroll
        for (int i = 0; i < 16; ++i) {
            const int i4 = tid + i * 256;
            const float4 v = ((const float4*)hsrc)[i4];
            const int e = i4 * 4, row = e >> 7, col = e & 127;
            uint2 st; st.x = pk2(v.x, v.y); st.y = pk2(v.z, v.w);
            *(uint2*)&hbf[row * 136 + col] = st;
            if (i < 8) { ms0.x += v.x; ms0.y += v.y; ms0.z += v.z; ms0.w += v.w; }
            else       { ms1.x += v.x; ms1.y += v.y; ms1.z += v.z; ms1.w += v.w; }
        }
        const int mc = (tid * 4) & 127;
        atomicAdd(&meanv[mc],           ms0.x); atomicAdd(&meanv[mc + 1],       ms0.y);
        atomicAdd(&meanv[mc + 2],       ms0.z); atomicAdd(&meanv[mc + 3],       ms0.w);
        atomicAdd(&meanv[128 + mc],     ms1.x); atomicAdd(&meanv[128 + mc + 1], ms1.y);
        atomicAdd(&meanv[128 + mc + 2], ms1.z); atomicAdd(&meanv[128 + mc + 3], ms1.w);
    }
    // ---- stage wb <- wb1 (16B chunks)
    #pragma unroll
    for (int i = 0; i < 8; ++i) {
        const int ch = tid + i * 256;
        const int e = ch * 8, row = e >> 7, col = e & 127;
        *(uint4*)&wb[row * 136 + col] = ((const uint4*)wb1g)[ch];
    }
    __syncthreads();

    // ---- g1[s][col] = mean[s].W1[col] / 64 + W1_b + W2_b   (all 256 threads)
    {
        const int col = tid & 127, s = tid >> 7;
        const float4* wr = (const float4*)(W1 + col * 128);
        const float4* mv = (const float4*)(meanv + s * 128);
        float acc = 0.f;
        #pragma unroll 8
        for (int k4 = 0; k4 < 32; ++k4) {
            const float4 wv = wr[k4], m4 = mv[k4];
            acc += m4.x * wv.x + m4.y * wv.y + m4.z * wv.z + m4.w * wv.w;
        }
        g1s[tid] = W1b[col] + W2b[col] + acc * (1.f / 64.f);
        // visible at the post-GEMM1 barrier, well before first use
    }

    // ---- GEMM1: ph = tanh(hidden @ Wpa^T + pp)  M=32/wave, N=128, K=128
    bf16x8 af[2][4];
    #pragma unroll
    for (int m = 0; m < 2; ++m)
        #pragma unroll
        for (int kk = 0; kk < 4; ++kk)
            af[m][kk] = *(const bf16x8*)&hbf[(R + 16 * m + c) * 136 + kk * 32 + g * 8];
    f32x4 acc1[2][8] = {};
    #pragma unroll
    for (int n = 0; n < 8; ++n) {
        #pragma unroll
        for (int kk = 0; kk < 4; ++kk) {
            const bf16x8 bfr = *(const bf16x8*)&wb[(16 * n + c) * 136 + kk * 32 + g * 8];
            acc1[0][n] = MFMA(af[0][kk], bfr, acc1[0][n], 0, 0, 0);
            acc1[1][n] = MFMA(af[1][kk], bfr, acc1[1][n], 0, 0, 0);
        }
    }
    {
        const float K2 = 2.885390081777927f;        // 2*log2(e)
        const float* pkp[2][4];
        #pragma unroll
        for (int m = 0; m < 2; ++m)
            #pragma unroll
            for (int r = 0; r < 4; ++r)
                pkp[m][r] = ppK + rps[R + 16 * m + 4 * g + r] * 128 + c;
        #pragma unroll
        for (int m = 0; m < 2; ++m)
            #pragma unroll
            for (int n = 0; n < 8; ++n)
                #pragma unroll
                for (int r = 0; r < 4; ++r) {
                    const float arg = fmaf(acc1[m][n][r], K2, pkp[m][r][16 * n]);
                    const float e2 = __builtin_amdgcn_exp2f(arg);
                    const float rc = __builtin_amdgcn_rcpf(e2 + 1.f);
                    const float th = fmaf(-2.f, rc, 1.f);       // tanh
                    // in-place over own wave's rows
                    hbf[(R + 16 * m + 4 * g + r) * 136 + 16 * n + c] = f2b1(th);
                }
    }
    __syncthreads();   // all wb1 B-reads done; ph committed; g1s visible

    // ---- GEMM2 A-frags (ph), then restage wb <- wb2
    bf16x8 af2[2][4];
    #pragma unroll
    for (int m = 0; m < 2; ++m)
        #pragma unroll
        for (int kk = 0; kk < 4; ++kk)
            af2[m][kk] = *(const bf16x8*)&hbf[(R + 16 * m + c) * 136 + kk * 32 + g * 8];
    #pragma unroll
    for (int i = 0; i < 8; ++i) {
        const int ch = tid + i * 256;
        const int e = ch * 8, row = e >> 7, col = e & 127;
        *(uint4*)&wb[row * 136 + col] = ((const uint4*)wb2g)[ch];
    }
    __syncthreads();

    // ---- GEMM2: gate = sigmoid(g1 + ph @ W2^T); alpha = gate.qw + qb
    f32x4 acc2[2][8] = {};
    #pragma unroll
    for (int n = 0; n < 8; ++n) {
        #pragma unroll
        for (int kk = 0; kk < 4; ++kk) {
            const bf16x8 bfr = *(const bf16x8*)&wb[(16 * n + c) * 136 + kk * 32 + g * 8];
            acc2[0][n] = MFMA(af2[0][kk], bfr, acc2[0][n], 0, 0, 0);
            acc2[1][n] = MFMA(af2[1][kk], bfr, acc2[1][n], 0, 0, 0);
        }
    }
    {
        const float K1 = 1.4426950408889634f;       // log2(e)
        const int sw = w >> 1;                      // wave's session
        float garr[8], qarr[8];
        #pragma unroll
        for (int n = 0; n < 8; ++n) {
            garr[n] = -K1 * g1s[sw * 128 + 16 * n + c];
            qarr[n] = qws[16 * n + c];
        }
        float prt[2][4] = {};
        #pragma unroll
        for (int m = 0; m < 2; ++m)
            #pragma unroll
            for (int n = 0; n < 8; ++n)
                #pragma unroll
                for (int r = 0; r < 4; ++r) {
                    const float arg = fmaf(acc2[m][n][r], -K1, garr[n]);
                    const float e2 = __builtin_amdgcn_exp2f(arg);
                    const float rc = __builtin_amdgcn_rcpf(e2 + 1.f);   // sigmoid
                    prt[m][r] = fmaf(rc, qarr[n], prt[m][r]);
                }
        #pragma unroll
        for (int msk = 1; msk <= 8; msk <<= 1)
            #pragma unroll
            for (int m = 0; m < 2; ++m)
                #pragma unroll
                for (int r = 0; r < 4; ++r)
                    prt[m][r] += __shfl_xor(prt[m][r], msk, 64);
        if (c == 0) {
            const float qbv = qb[0];
            #pragma unroll
            for (int m = 0; m < 2; ++m)
                #pragma unroll
                for (int r = 0; r < 4; ++r)
                    alphas[R + 16 * m + 4 * g + r] = prt[m][r] + qbv;
        }
    }
    __syncthreads();

    // ---- out[s] = sum_t alpha_t * hidden[t]  (fp32 global, L2/L3-hot;
    //      thread = (session p, column h); coalesced across lanes)
    {
        const int h = tid & 127, p = tid >> 7;
        const float* hs = hsrc + p * (64 * 128) + h;
        float accf = 0.f;
        #pragma unroll 8
        for (int t = 0; t < 64; ++t)
            accf = fmaf(alphas[64 * p + t], hs[t * 128], accf);
        out[(size_t)blk * 256 + tid] = accf;
    }
}

// ---------------------------------------------------------------------------
extern "C" void kernel_launch(void* const* d_in, const int* in_sizes, int n_in,
                              void* d_out, int out_size, void* d_ws, size_t ws_size,
                              hipStream_t stream)
{
    const float* hidden    = (const float*)d_in[0];
    const float* pos_table = (const float*)d_in[1];
    const float* Wpw       = (const float*)d_in[2];
    const float* Wpb       = (const float*)d_in[3];
    const float* W1w       = (const float*)d_in[4];
    const float* W1b       = (const float*)d_in[5];
    const float* W2w       = (const float*)d_in[6];
    const float* W2b       = (const float*)d_in[7];
    const float* qw        = (const float*)d_in[8];
    const float* qb        = (const float*)d_in[9];
    const int*   rpos      = (const int*)d_in[11];
    float* out = (float*)d_out;

    const int B = in_sizes[10];              // sessions (8192)

    // workspace layout (98816 B total)
    char* wsb = (char*)d_ws;
    float* ppK = (float*)wsb;                        // 65*128*4 = 33280
    u16* wb1   = (u16*)(wsb + 33280);                // 32768
    u16* wb2   = (u16*)(wsb + 33280 + 32768);        // 32768

    prep_kernel<<<193, 128, 0, stream>>>(pos_table, Wpw, Wpb, W2w,
                                         ppK, wb1, wb2);
    fused_kernel<<<B / 2, 256, 0, stream>>>(hidden, rpos, W1w, W1b, W2b, qw, qb,
                                            ppK, wb1, wb2, out);
}